// Round 6
// baseline (239.067 us; speedup 1.0000x reference)
//
#include <hip/hip_runtime.h>

typedef _Float16 f16;
typedef _Float16 f16x4 __attribute__((ext_vector_type(4)));
typedef _Float16 f16x8 __attribute__((ext_vector_type(8)));
typedef float f32x4 __attribute__((ext_vector_type(4)));

#define LOG2E 1.4426950408889634f
#define SCL   (1.4426950408889634f / 32.0f)   // SCALE^2 * log2(e) folded
#define TH_RAW 177.445f                        // 8.0 / SCL : defer-max threshold

// ---------------- K0: fused transposes ---------------------------------------
// bx<32: x[b][2048][256] f32 -> xt[b][256][2048] f16   (tile n0=bx*64, d0=by*64)
// bx>=32: W[s][256][768] f32 -> Wt[s][512][256] f16    (n0=(bx-32)*64, k0=by*64)
__global__ __launch_bounds__(256) void k_stage(const float* __restrict__ x,
    const float* __restrict__ Wq, const float* __restrict__ Wa,
    f16* __restrict__ xt, f16* __restrict__ Wt) {
  __shared__ f16 tile[64][65];
  int t = threadIdx.x, c = t & 63, rg = t >> 6;
  if (blockIdx.x < 32) {
    int n0 = blockIdx.x * 64, d0 = blockIdx.y * 64, b = blockIdx.z;
#pragma unroll
    for (int r = 0; r < 16; ++r) {
      int row = r * 4 + rg;
      tile[row][c] = (f16)x[((size_t)b * 2048 + n0 + row) * 256 + d0 + c];
    }
    __syncthreads();
#pragma unroll
    for (int r = 0; r < 16; ++r) {
      int drow = r * 4 + rg;
      xt[((size_t)b * 256 + d0 + drow) * 2048 + n0 + c] = tile[c][drow];
    }
  } else {
    int n0 = (blockIdx.x - 32) * 64, k0 = blockIdx.y * 64, s = blockIdx.z;
    const float* W = s ? Wa : Wq;
    f16* dst = Wt + (size_t)s * 512 * 256;
#pragma unroll
    for (int r = 0; r < 16; ++r) {
      int krow = r * 4 + rg;
      tile[krow][c] = (f16)W[(size_t)(k0 + krow) * 768 + n0 + c];
    }
    __syncthreads();
#pragma unroll
    for (int r = 0; r < 16; ++r) {
      int nrow = r * 4 + rg;
      dst[(size_t)(n0 + nrow) * 256 + k0 + c] = tile[c][nrow];
    }
  }
}

// ---------------- K1: Q/K projections, global-direct (no LDS) ---------------
// Out: Q*/K* as [b*8+h][2048][32] f16.
__global__ __launch_bounds__(256) void k_proj(const float* __restrict__ x,
    const float* __restrict__ af, const f16* __restrict__ Wt,
    f16* __restrict__ Qs, f16* __restrict__ Ks,
    f16* __restrict__ Qa, f16* __restrict__ Ka) {
  int mt = blockIdx.x, nt = blockIdx.y, s = blockIdx.z;
  const float* A = s ? af : x;
  const f16* W = Wt + (size_t)s * 512 * 256;
  f16* Qd = s ? Qa : Qs;
  f16* Kd = s ? Ka : Ks;
  int t = threadIdx.x, wv = t >> 6, ln = t & 63, cl = ln & 15, g = ln >> 4;
  int m0 = mt * 64, n0 = nt * 64;
  const float* arow = A + (size_t)(m0 + wv * 16 + cl) * 256 + g * 8;
  const f16* wb = W + (size_t)n0 * 256 + g * 8;
  f32x4 z4 = {0.f, 0.f, 0.f, 0.f};
  f32x4 acc[4] = {z4, z4, z4, z4};
#pragma unroll
  for (int k32 = 0; k32 < 8; ++k32) {
    float4 u = *(const float4*)(arow + k32 * 32);
    float4 v = *(const float4*)(arow + k32 * 32 + 4);
    f16x8 a = { (f16)u.x, (f16)u.y, (f16)u.z, (f16)u.w,
                (f16)v.x, (f16)v.y, (f16)v.z, (f16)v.w };
#pragma unroll
    for (int n4 = 0; n4 < 4; ++n4) {
      f16x8 bf = *(const f16x8*)(wb + (size_t)(n4 * 16 + cl) * 256 + k32 * 32);
      acc[n4] = __builtin_amdgcn_mfma_f32_16x16x32_f16(a, bf, acc[n4], 0, 0, 0);
    }
  }
#pragma unroll
  for (int n4 = 0; n4 < 4; ++n4) {
    int c = n0 + n4 * 16 + cl;               // 0..511 (Q: 0-255, K: 256-511)
    int head = (c & 255) >> 5, d = c & 31;
    f16* dst = (c < 256) ? Qd : Kd;
#pragma unroll
    for (int r = 0; r < 4; ++r) {
      int m = m0 + wv * 16 + g * 4 + r;
      int bb = m >> 11, nn = m & 2047;
      dst[(((size_t)bb * 8 + head) * 2048 + nn) * 32 + d] = (f16)acc[n4][r];
    }
  }
}

// ---------------- K2: fused dual-score flash attention (wave-specialized) ---
// blockIdx.x == 0: attn0 side-task (row-0 probs) riding along concurrently.
// blockIdx.x >= 1: flash block (qt = bx-1). 8 waves: waves 0-3 = SCORE
// (stripe sw: dual QK^T + softmax -> PL[buf]); waves 4-7 = PV (dd slice
// sw*64, consume PL[buf^1], lagged one tile). K tiles cooperatively staged
// (512 threads x 16B), double-buffered; one barrier/K-tile. No duplicated
// softmax; per-wave chains ~half of the combined version; 16 waves/CU.
// amdgpu_waves_per_eu(4,4): pin VGPR cap at 128, forbid the 64-reg squeeze
// that spilled R4/R5 (observed via WRITE_SIZE inflation).
__global__ __launch_bounds__(512)
__attribute__((amdgpu_waves_per_eu(4, 4)))
void k_flash(const f16* __restrict__ Qs,
    const f16* __restrict__ Ks, const f16* __restrict__ Qa,
    const f16* __restrict__ Ka, const f16* __restrict__ xt,
    float* __restrict__ out, float* __restrict__ out_cls,
    float* __restrict__ attn0) {
  __shared__ f16 KaL[2][64][40];     // pitch 80B: conflict-free A-frag reads
  __shared__ f16 KsL[2][64][40];
  __shared__ f16 PL[2][64][72];      // [q][j], pitch 144B
  __shared__ float alphaL[2][64] __attribute__((aligned(16)));
  __shared__ int   rsF[2][4] __attribute__((aligned(16)));  // per-stripe rescale flag
  __shared__ float lL[64];
  int h = blockIdx.y, b = blockIdx.z;
  int bh = b * 8 + h;
  int t = threadIdx.x;

  if (blockIdx.x == 0) {
    // ---- attn0: probs for query row 0, 512 threads, LDS aliased ----
    float* qa_s = &alphaL[0][0];     // 32 floats
    float* qs_s = &alphaL[1][0];     // 32 floats
    float* red  = (float*)&PL[0][0][0];  // 512 floats (2KB of 18KB)
    if (t < 32) {
      qa_s[t] = (float)Qa[(size_t)bh * 2048 * 32 + t];
      qs_s[t] = (float)Qs[(size_t)bh * 2048 * 32 + t];
    }
    __syncthreads();
    float sv[4];
#pragma unroll
    for (int r = 0; r < 4; ++r) {
      int j = r * 512 + t;
      const f16x8* ka8 = (const f16x8*)&Ka[((size_t)bh * 2048 + j) * 32];
      const f16x8* ks8 = (const f16x8*)&Ks[((size_t)bh * 2048 + j) * 32];
      float da = 0.f, ds = 0.f;
#pragma unroll
      for (int c = 0; c < 4; ++c) {
        f16x8 va = ka8[c], vs = ks8[c];
#pragma unroll
        for (int d = 0; d < 8; ++d) {
          da += qa_s[c * 8 + d] * (float)va[d];
          ds += qs_s[c * 8 + d] * (float)vs[d];
        }
      }
      sv[r] = da * ds * (1.f / 32.f);
    }
    float mx = fmaxf(fmaxf(sv[0], sv[1]), fmaxf(sv[2], sv[3]));
    red[t] = mx;
    __syncthreads();
    for (int st = 256; st > 0; st >>= 1) {
      if (t < st) red[t] = fmaxf(red[t], red[t + st]);
      __syncthreads();
    }
    float m = red[0];
    __syncthreads();
    float e[4], sum = 0.f;
#pragma unroll
    for (int r = 0; r < 4; ++r) {
      e[r] = exp2f((sv[r] - m) * LOG2E);
      sum += e[r];
    }
    red[t] = sum;
    __syncthreads();
    for (int st = 256; st > 0; st >>= 1) {
      if (t < st) red[t] += red[t + st];
      __syncthreads();
    }
    float l = red[0];
#pragma unroll
    for (int r = 0; r < 4; ++r)
      attn0[(size_t)b * 16384 + h * 2048 + r * 512 + t] = e[r] / l;
    return;
  }

  int qt = blockIdx.x - 1;
  int wv = t >> 6, ln = t & 63, cl = ln & 15, g = ln >> 4;
  bool isScore = wv < 4;
  int sw = wv & 3;                   // score stripe / PV dd-slice index
  f32x4 z4 = {0.f, 0.f, 0.f, 0.f};

  // --- K staging: threads 0-255 stage Ka, 256-511 stage Ks ---
  int sel = t >> 8;                  // wave-uniform
  int krow = (t >> 2) & 63, koff = (t & 3) * 8;
  f16 (*KLsel)[64][40] = sel ? KsL : KaL;
  const f16* kSrc = (sel ? Ks : Ka) + ((size_t)bh * 2048 + krow) * 32 + koff;

  // --- score-wave state ---
  f16x8 qsf, qaf;
  float m_run = -3.0e38f, l_lane = 0.f;
  if (isScore) {
    int qrow0 = qt * 64 + sw * 16;
    qsf = *(const f16x8*)&Qs[((size_t)bh * 2048 + qrow0 + cl) * 32 + g * 8];
    qaf = *(const f16x8*)&Qa[((size_t)bh * 2048 + qrow0 + cl) * 32 + g * 8];
  }
  float tv[16];

  // --- PV-wave state ---
  f32x4 acc[4][4];
#pragma unroll
  for (int i = 0; i < 4; ++i)
#pragma unroll
    for (int j = 0; j < 4; ++j) acc[i][j] = z4;
  const f16* xb = xt + ((size_t)b * 256 + sw * 64) * 2048;
  f16x8 xf[2][4];

  // ---- score MFMAs from KL[buf] -> tv (raw domain) ----
  auto SCORE_MM = [&](int buf) {
#pragma unroll
    for (int jt = 0; jt < 4; ++jt) {
      f16x8 kaf = *(const f16x8*)&KaL[buf][jt * 16 + cl][g * 8];
      f16x8 ksf = *(const f16x8*)&KsL[buf][jt * 16 + cl][g * 8];
      f32x4 za = __builtin_amdgcn_mfma_f32_16x16x32_f16(kaf, qaf, z4, 0, 0, 0);
      f32x4 zs = __builtin_amdgcn_mfma_f32_16x16x32_f16(ksf, qsf, z4, 0, 0, 0);
#pragma unroll
      for (int r = 0; r < 4; ++r) tv[jt * 4 + r] = za[r] * zs[r];
    }
  };

  // ---- softmax finish; zero-shuffle common path; deferred l-reduction ----
  auto SCORE_FIN = [&](int buf) {
    float a0 = fmaxf(tv[0], tv[1]),   a1 = fmaxf(tv[2], tv[3]);
    float a2 = fmaxf(tv[4], tv[5]),   a3 = fmaxf(tv[6], tv[7]);
    float a4 = fmaxf(tv[8], tv[9]),   a5 = fmaxf(tv[10], tv[11]);
    float a6 = fmaxf(tv[12], tv[13]), a7 = fmaxf(tv[14], tv[15]);
    float b0 = fmaxf(a0, a1), b1 = fmaxf(a2, a3);
    float b2 = fmaxf(a4, a5), b3 = fmaxf(a6, a7);
    float lmax = fmaxf(fmaxf(b0, b1), fmaxf(b2, b3));
    int wflag = 0;
    if (__any(lmax > m_run + TH_RAW)) {      // rare: real max growth
      float tm = fmaxf(lmax, __shfl_xor(lmax, 16, 64));
      tm = fmaxf(tm, __shfl_xor(tm, 32, 64));
      float m_new = fmaxf(m_run, tm);
      float alpha = exp2f((m_run - m_new) * SCL);
      l_lane *= alpha;
      m_run = m_new;
      if (g == 0) alphaL[buf][sw * 16 + cl] = alpha;
      wflag = 1;
    }
    float mS = m_run * SCL;
    float p[16];
#pragma unroll
    for (int i = 0; i < 16; ++i) p[i] = exp2f(fmaf(tv[i], SCL, -mS));
    float s0 = p[0] + p[1],   s1 = p[2] + p[3];
    float s2 = p[4] + p[5],   s3 = p[6] + p[7];
    float s4 = p[8] + p[9],   s5 = p[10] + p[11];
    float s6 = p[12] + p[13], s7 = p[14] + p[15];
    float u0 = s0 + s1, u1 = s2 + s3, u2 = s4 + s5, u3 = s6 + s7;
    l_lane += (u0 + u1) + (u2 + u3);
#pragma unroll
    for (int jt = 0; jt < 4; ++jt) {
      auto lo = __builtin_amdgcn_cvt_pkrtz(p[jt * 4 + 0], p[jt * 4 + 1]);
      auto hi = __builtin_amdgcn_cvt_pkrtz(p[jt * 4 + 2], p[jt * 4 + 3]);
      f16x4 pk = { (f16)lo[0], (f16)lo[1], (f16)hi[0], (f16)hi[1] };
      *(f16x4*)&PL[buf][sw * 16 + cl][jt * 16 + g * 4] = pk;
    }
    if (ln == 0) rsF[buf][sw] = wflag;
  };

  // ---- Xt B-frag loads for PV tile kt (wave's 64-dd slice) ----
  auto XFLOAD = [&](int kt) {
#pragma unroll
    for (int ks2 = 0; ks2 < 2; ++ks2)
#pragma unroll
      for (int ddt = 0; ddt < 4; ++ddt)
        xf[ks2][ddt] = *(const f16x8*)(xb + (size_t)(ddt * 16 + cl) * 2048 +
                                       kt * 64 + ks2 * 32 + g * 8);
  };

  // ---- PV for PL[pbuf] (lagged tile), with gated rescale ----
  auto PVDO = [&](int pbuf) {
    int4 fl = *(const int4*)&rsF[pbuf][0];
    int flq[4] = { fl.x, fl.y, fl.z, fl.w };
#pragma unroll
    for (int qt2 = 0; qt2 < 4; ++qt2) {
      if (flq[qt2]) {
        f32x4 a4 = *(const f32x4*)&alphaL[pbuf][qt2 * 16 + g * 4];
#pragma unroll
        for (int ddt = 0; ddt < 4; ++ddt)
#pragma unroll
          for (int r = 0; r < 4; ++r) acc[qt2][ddt][r] *= a4[r];
      }
    }
#pragma unroll
    for (int ks2 = 0; ks2 < 2; ++ks2) {
      f16x8 pf[4];
#pragma unroll
      for (int qt2 = 0; qt2 < 4; ++qt2)
        pf[qt2] = *(const f16x8*)&PL[pbuf][qt2 * 16 + cl][ks2 * 32 + g * 8];
#pragma unroll
      for (int ddt = 0; ddt < 4; ++ddt)
#pragma unroll
        for (int qt2 = 0; qt2 < 4; ++qt2)
          acc[qt2][ddt] = __builtin_amdgcn_mfma_f32_16x16x32_f16(
              pf[qt2], xf[ks2][ddt], acc[qt2][ddt], 0, 0, 0);
    }
  };

  // ---- prologue: stage K tile 0 ----
  *(f16x8*)&KLsel[0][krow][koff] = *(const f16x8*)kSrc;
  __syncthreads();

  // ---- main loop: one barrier per K-tile ----
  for (int k = 0; k < 32; ++k) {
    int buf = k & 1;
    f16x8 kreg;
    if (k < 31) kreg = *(const f16x8*)(kSrc + (size_t)(k + 1) * 2048);
    if (isScore) {
      SCORE_MM(buf);                 // ds_read K[buf] + 8 MFMA
      SCORE_FIN(buf);                // softmax -> PL[buf]/alphaL[buf]/rsF[buf]
    } else if (k > 0) {
      XFLOAD(k - 1);                 // global Xt frags (L2-resident)
      PVDO(buf ^ 1);                 // consume PL[(k-1)&1] + 32 MFMA
    }
    if (k < 31) *(f16x8*)&KLsel[buf ^ 1][krow][koff] = kreg;
    __syncthreads();
  }

  // ---- drain: score waves reduce l; PV waves finish tile 31 ----
  if (isScore) {
    l_lane += __shfl_xor(l_lane, 16, 64);
    l_lane += __shfl_xor(l_lane, 32, 64);
    if (g == 0) lL[sw * 16 + cl] = l_lane;
  } else {
    XFLOAD(31);
    PVDO(1);
  }
  __syncthreads();

  // ---- epilogue: PV waves write out ----
  if (!isScore) {
#pragma unroll
    for (int qt2 = 0; qt2 < 4; ++qt2) {
#pragma unroll
      for (int r = 0; r < 4; ++r) {
        float linv = 1.0f / lL[qt2 * 16 + g * 4 + r];
        int q = qt * 64 + qt2 * 16 + g * 4 + r;
#pragma unroll
        for (int ddt = 0; ddt < 4; ++ddt) {
          float v = acc[qt2][ddt][r] * linv;
          int col = h * 256 + sw * 64 + ddt * 16 + cl;
          out[((size_t)b * 2048 + q) * 2048 + col] = v;
          if (q == 0) out_cls[(size_t)b * 2048 + col] = v;
        }
      }
    }
  }
}

extern "C" void kernel_launch(void* const* d_in, const int* in_sizes, int n_in,
                              void* d_out, int out_size, void* d_ws, size_t ws_size,
                              hipStream_t stream) {
  const float* x  = (const float*)d_in[0];
  const float* af = (const float*)d_in[1];
  const float* Wq = (const float*)d_in[2];
  const float* Wa = (const float*)d_in[3];
  // ws (f16): Qs|Ks|Qa|Ka (4x1M) | xt (1M) | Wt (256K)  ~= 10.5 MB
  const size_t QK = (size_t)2 * 8 * 2048 * 32;
  f16* Qs = (f16*)d_ws;
  f16* Ks = Qs + QK;
  f16* Qa = Ks + QK;
  f16* Ka = Qa + QK;
  f16* xt = Ka + QK;
  f16* Wt = xt + QK;
  float* out     = (float*)d_out;
  float* out_cls = out + (size_t)2 * 2048 * 2048;
  float* attn0   = out_cls + 2 * 2048;

  k_stage<<<dim3(40, 4, 2), 256, 0, stream>>>(x, Wq, Wa, xt, Wt);
  k_proj<<<dim3(64, 8, 2), 256, 0, stream>>>(x, af, Wt, Qs, Ks, Qa, Ka);
  k_flash<<<dim3(33, 8, 2), 512, 0, stream>>>(Qs, Ks, Qa, Ka, xt, out, out_cls,
                                              attn0);
}

// Round 7
// 182.374 us; speedup vs baseline: 1.3109x; 1.3109x over previous
//
#include <hip/hip_runtime.h>

typedef _Float16 f16;
typedef _Float16 f16x4 __attribute__((ext_vector_type(4)));
typedef _Float16 f16x8 __attribute__((ext_vector_type(8)));
typedef float f32x4 __attribute__((ext_vector_type(4)));

#define LOG2E 1.4426950408889634f
#define SCL   (1.4426950408889634f / 32.0f)   // SCALE^2 * log2(e) folded
#define TH_RAW 177.445f                        // 8.0 / SCL : defer-max threshold

// ---------------- K0: fused transposes ---------------------------------------
// bx<32: x[b][2048][256] f32 -> xt[b][256][2048] f16   (tile n0=bx*64, d0=by*64)
// bx>=32: W[s][256][768] f32 -> Wt[s][512][256] f16    (n0=(bx-32)*64, k0=by*64)
__global__ __launch_bounds__(256) void k_stage(const float* __restrict__ x,
    const float* __restrict__ Wq, const float* __restrict__ Wa,
    f16* __restrict__ xt, f16* __restrict__ Wt) {
  __shared__ f16 tile[64][65];
  int t = threadIdx.x, c = t & 63, rg = t >> 6;
  if (blockIdx.x < 32) {
    int n0 = blockIdx.x * 64, d0 = blockIdx.y * 64, b = blockIdx.z;
#pragma unroll
    for (int r = 0; r < 16; ++r) {
      int row = r * 4 + rg;
      tile[row][c] = (f16)x[((size_t)b * 2048 + n0 + row) * 256 + d0 + c];
    }
    __syncthreads();
#pragma unroll
    for (int r = 0; r < 16; ++r) {
      int drow = r * 4 + rg;
      xt[((size_t)b * 256 + d0 + drow) * 2048 + n0 + c] = tile[c][drow];
    }
  } else {
    int n0 = (blockIdx.x - 32) * 64, k0 = blockIdx.y * 64, s = blockIdx.z;
    const float* W = s ? Wa : Wq;
    f16* dst = Wt + (size_t)s * 512 * 256;
#pragma unroll
    for (int r = 0; r < 16; ++r) {
      int krow = r * 4 + rg;
      tile[krow][c] = (f16)W[(size_t)(k0 + krow) * 768 + n0 + c];
    }
    __syncthreads();
#pragma unroll
    for (int r = 0; r < 16; ++r) {
      int nrow = r * 4 + rg;
      dst[(size_t)(n0 + nrow) * 256 + k0 + c] = tile[c][nrow];
    }
  }
}

// ---------------- K1: Q/K projections, global-direct (no LDS) ---------------
// Out: Q*/K* as [b*8+h][2048][32] f16.
__global__ __launch_bounds__(256) void k_proj(const float* __restrict__ x,
    const float* __restrict__ af, const f16* __restrict__ Wt,
    f16* __restrict__ Qs, f16* __restrict__ Ks,
    f16* __restrict__ Qa, f16* __restrict__ Ka) {
  int mt = blockIdx.x, nt = blockIdx.y, s = blockIdx.z;
  const float* A = s ? af : x;
  const f16* W = Wt + (size_t)s * 512 * 256;
  f16* Qd = s ? Qa : Qs;
  f16* Kd = s ? Ka : Ks;
  int t = threadIdx.x, wv = t >> 6, ln = t & 63, cl = ln & 15, g = ln >> 4;
  int m0 = mt * 64, n0 = nt * 64;
  const float* arow = A + (size_t)(m0 + wv * 16 + cl) * 256 + g * 8;
  const f16* wb = W + (size_t)n0 * 256 + g * 8;
  f32x4 z4 = {0.f, 0.f, 0.f, 0.f};
  f32x4 acc[4] = {z4, z4, z4, z4};
#pragma unroll
  for (int k32 = 0; k32 < 8; ++k32) {
    float4 u = *(const float4*)(arow + k32 * 32);
    float4 v = *(const float4*)(arow + k32 * 32 + 4);
    f16x8 a = { (f16)u.x, (f16)u.y, (f16)u.z, (f16)u.w,
                (f16)v.x, (f16)v.y, (f16)v.z, (f16)v.w };
#pragma unroll
    for (int n4 = 0; n4 < 4; ++n4) {
      f16x8 bf = *(const f16x8*)(wb + (size_t)(n4 * 16 + cl) * 256 + k32 * 32);
      acc[n4] = __builtin_amdgcn_mfma_f32_16x16x32_f16(a, bf, acc[n4], 0, 0, 0);
    }
  }
#pragma unroll
  for (int n4 = 0; n4 < 4; ++n4) {
    int c = n0 + n4 * 16 + cl;               // 0..511 (Q: 0-255, K: 256-511)
    int head = (c & 255) >> 5, d = c & 31;
    f16* dst = (c < 256) ? Qd : Kd;
#pragma unroll
    for (int r = 0; r < 4; ++r) {
      int m = m0 + wv * 16 + g * 4 + r;
      int bb = m >> 11, nn = m & 2047;
      dst[(((size_t)bb * 8 + head) * 2048 + nn) * 32 + d] = (f16)acc[n4][r];
    }
  }
}

// ---------------- K2: fused dual-score flash attention (KV tile = 128) ------
// blockIdx.x == 0: attn0 side task (row-0 probs). bx>=1: flash, qt = bx-1.
// Block = 4 waves, 64 q-rows. Wave wv: scores q-stripe wv (16 rows) over the
// 128-key tile; PV for all 64 q-rows x 64-dd slice wv*64, lagged one tile,
// split in two 64-key halves (xfA issued at iter top: covered by score+softmax;
// xfB after SCORE_MM: covered by softmax). 16 iters -> per-iter fixed costs
// (barrier, ballot, LDS latency, K-commit) halved vs the 64-key tile.
// 256-thread blocks + launch_bounds(256,2): the only shape the allocator has
// not spilled (512-thread got 64 VGPRs + scratch twice: R4/R6).
__global__ __launch_bounds__(256, 2) void k_flash(const f16* __restrict__ Qs,
    const f16* __restrict__ Ks, const f16* __restrict__ Qa,
    const f16* __restrict__ Ka, const f16* __restrict__ xt,
    float* __restrict__ out, float* __restrict__ out_cls,
    float* __restrict__ attn0) {
  __shared__ f16 KaL[2][128][40];    // pitch 80B
  __shared__ f16 KsL[2][128][40];
  __shared__ f16 PL[2][64][136];     // [q][j 0..127], pitch 272B (16B mult)
  __shared__ float alphaL[2][64] __attribute__((aligned(16)));
  __shared__ int   rsF[2][4] __attribute__((aligned(16)));
  __shared__ float lL[64];
  int h = blockIdx.y, b = blockIdx.z;
  int bh = b * 8 + h;
  int t = threadIdx.x;

  if (blockIdx.x == 0) {
    // ---- attn0: probs for query row 0 (256 threads, LDS aliased) ----
    float* qa_s = &alphaL[0][0];
    float* qs_s = &alphaL[1][0];
    float* red  = (float*)&PL[0][0][0];    // 256 floats
    if (t < 32) {
      qa_s[t] = (float)Qa[(size_t)bh * 2048 * 32 + t];
      qs_s[t] = (float)Qs[(size_t)bh * 2048 * 32 + t];
    }
    __syncthreads();
    float sv[8];
#pragma unroll
    for (int r = 0; r < 8; ++r) {
      int j = r * 256 + t;
      const f16x8* ka8 = (const f16x8*)&Ka[((size_t)bh * 2048 + j) * 32];
      const f16x8* ks8 = (const f16x8*)&Ks[((size_t)bh * 2048 + j) * 32];
      float da = 0.f, ds = 0.f;
#pragma unroll
      for (int c = 0; c < 4; ++c) {
        f16x8 va = ka8[c], vs = ks8[c];
#pragma unroll
        for (int d = 0; d < 8; ++d) {
          da += qa_s[c * 8 + d] * (float)va[d];
          ds += qs_s[c * 8 + d] * (float)vs[d];
        }
      }
      sv[r] = da * ds * (1.f / 32.f);
    }
    float mx = sv[0];
#pragma unroll
    for (int r = 1; r < 8; ++r) mx = fmaxf(mx, sv[r]);
    red[t] = mx;
    __syncthreads();
    for (int st = 128; st > 0; st >>= 1) {
      if (t < st) red[t] = fmaxf(red[t], red[t + st]);
      __syncthreads();
    }
    float m = red[0];
    __syncthreads();
    float e[8], sum = 0.f;
#pragma unroll
    for (int r = 0; r < 8; ++r) {
      e[r] = exp2f((sv[r] - m) * LOG2E);
      sum += e[r];
    }
    red[t] = sum;
    __syncthreads();
    for (int st = 128; st > 0; st >>= 1) {
      if (t < st) red[t] += red[t + st];
      __syncthreads();
    }
    float l = red[0];
#pragma unroll
    for (int r = 0; r < 8; ++r)
      attn0[(size_t)b * 16384 + h * 2048 + r * 256 + t] = e[r] / l;
    return;
  }

  int qt = blockIdx.x - 1;
  int wv = t >> 6, ln = t & 63, cl = ln & 15, g = ln >> 4;
  int qrow0 = qt * 64 + wv * 16;
  f16x8 qsf = *(const f16x8*)&Qs[((size_t)bh * 2048 + qrow0 + cl) * 32 + g * 8];
  f16x8 qaf = *(const f16x8*)&Qa[((size_t)bh * 2048 + qrow0 + cl) * 32 + g * 8];
  f32x4 z4 = {0.f, 0.f, 0.f, 0.f};
  f32x4 acc[4][4];                   // [qt2][ddt]
#pragma unroll
  for (int i = 0; i < 4; ++i)
#pragma unroll
    for (int j = 0; j < 4; ++j) acc[i][j] = z4;
  float m_run = -3.0e38f, l_lane = 0.f;
  // K staging: thread t stages row t>>1, 32B at f16-offset (t&1)*16
  int r0 = t >> 1, hOff = (t & 1) * 16;
  const f16* kaSrc = Ka + ((size_t)bh * 2048 + r0) * 32 + hOff;
  const f16* ksSrc = Ks + ((size_t)bh * 2048 + r0) * 32 + hOff;
  const f16* xb = xt + ((size_t)b * 256 + wv * 64) * 2048;

  float tv[32];                      // raw dual scores (exp'd in place)
  f16x8 xfA[2][4], xfB[2][4];        // Xt frags: halves 0/1 of lagged tile

  auto SCORE_MM = [&](int buf) {
#pragma unroll
    for (int jt = 0; jt < 8; ++jt) {
      f16x8 kaf = *(const f16x8*)&KaL[buf][jt * 16 + cl][g * 8];
      f16x8 ksf = *(const f16x8*)&KsL[buf][jt * 16 + cl][g * 8];
      f32x4 za = __builtin_amdgcn_mfma_f32_16x16x32_f16(kaf, qaf, z4, 0, 0, 0);
      f32x4 zs = __builtin_amdgcn_mfma_f32_16x16x32_f16(ksf, qsf, z4, 0, 0, 0);
#pragma unroll
      for (int r = 0; r < 4; ++r) tv[jt * 4 + r] = za[r] * zs[r];
    }
  };

  auto SCORE_FIN = [&](int buf) {
    // tree max over 32 (depth 5)
    float m16[16];
#pragma unroll
    for (int i = 0; i < 16; ++i) m16[i] = fmaxf(tv[i], tv[i + 16]);
    float m8[8];
#pragma unroll
    for (int i = 0; i < 8; ++i) m8[i] = fmaxf(m16[i], m16[i + 8]);
    float m4[4];
#pragma unroll
    for (int i = 0; i < 4; ++i) m4[i] = fmaxf(m8[i], m8[i + 4]);
    float lmax = fmaxf(fmaxf(m4[0], m4[1]), fmaxf(m4[2], m4[3]));
    int wflag = 0;
    if (__any(lmax > m_run + TH_RAW)) {
      float tm = fmaxf(lmax, __shfl_xor(lmax, 16, 64));
      tm = fmaxf(tm, __shfl_xor(tm, 32, 64));
      float m_new = fmaxf(m_run, tm);
      float alpha = exp2f((m_run - m_new) * SCL);
      l_lane *= alpha;
      m_run = m_new;
      if (g == 0) alphaL[buf][wv * 16 + cl] = alpha;
      wflag = 1;
    }
    float mS = m_run * SCL;
#pragma unroll
    for (int i = 0; i < 32; ++i) tv[i] = exp2f(fmaf(tv[i], SCL, -mS));
    float s16[16];
#pragma unroll
    for (int i = 0; i < 16; ++i) s16[i] = tv[i] + tv[i + 16];
    float s8[8];
#pragma unroll
    for (int i = 0; i < 8; ++i) s8[i] = s16[i] + s16[i + 8];
    float s4[4];
#pragma unroll
    for (int i = 0; i < 4; ++i) s4[i] = s8[i] + s8[i + 4];
    l_lane += (s4[0] + s4[1]) + (s4[2] + s4[3]);
#pragma unroll
    for (int jt = 0; jt < 8; ++jt) {
      auto lo = __builtin_amdgcn_cvt_pkrtz(tv[jt * 4 + 0], tv[jt * 4 + 1]);
      auto hi = __builtin_amdgcn_cvt_pkrtz(tv[jt * 4 + 2], tv[jt * 4 + 3]);
      f16x4 pk = { (f16)lo[0], (f16)lo[1], (f16)hi[0], (f16)hi[1] };
      *(f16x4*)&PL[buf][wv * 16 + cl][jt * 16 + g * 4] = pk;
    }
    if (ln == 0) rsF[buf][wv] = wflag;
  };

  auto XFA = [&](int kt) {
#pragma unroll
    for (int ks2 = 0; ks2 < 2; ++ks2)
#pragma unroll
      for (int ddt = 0; ddt < 4; ++ddt)
        xfA[ks2][ddt] = *(const f16x8*)(xb + (size_t)(ddt * 16 + cl) * 2048 +
                                        kt * 128 + ks2 * 32 + g * 8);
  };
  auto XFB = [&](int kt) {
#pragma unroll
    for (int ks2 = 0; ks2 < 2; ++ks2)
#pragma unroll
      for (int ddt = 0; ddt < 4; ++ddt)
        xfB[ks2][ddt] = *(const f16x8*)(xb + (size_t)(ddt * 16 + cl) * 2048 +
                                        kt * 128 + 64 + ks2 * 32 + g * 8);
  };

  auto PVA = [&](int pbuf) {         // rescale + keys [0,64) of lagged tile
    int4 fl = *(const int4*)&rsF[pbuf][0];
    int flq[4] = { fl.x, fl.y, fl.z, fl.w };
#pragma unroll
    for (int qt2 = 0; qt2 < 4; ++qt2) {
      if (flq[qt2]) {
        f32x4 a4 = *(const f32x4*)&alphaL[pbuf][qt2 * 16 + g * 4];
#pragma unroll
        for (int ddt = 0; ddt < 4; ++ddt)
#pragma unroll
          for (int r = 0; r < 4; ++r) acc[qt2][ddt][r] *= a4[r];
      }
    }
#pragma unroll
    for (int ks = 0; ks < 2; ++ks) {
      f16x8 pf[4];
#pragma unroll
      for (int qt2 = 0; qt2 < 4; ++qt2)
        pf[qt2] = *(const f16x8*)&PL[pbuf][qt2 * 16 + cl][ks * 32 + g * 8];
#pragma unroll
      for (int ddt = 0; ddt < 4; ++ddt)
#pragma unroll
        for (int qt2 = 0; qt2 < 4; ++qt2)
          acc[qt2][ddt] = __builtin_amdgcn_mfma_f32_16x16x32_f16(
              pf[qt2], xfA[ks][ddt], acc[qt2][ddt], 0, 0, 0);
    }
  };
  auto PVB = [&](int pbuf) {         // keys [64,128) of lagged tile
#pragma unroll
    for (int ks = 0; ks < 2; ++ks) {
      f16x8 pf[4];
#pragma unroll
      for (int qt2 = 0; qt2 < 4; ++qt2)
        pf[qt2] = *(const f16x8*)&PL[pbuf][qt2 * 16 + cl][(2 + ks) * 32 + g * 8];
#pragma unroll
      for (int ddt = 0; ddt < 4; ++ddt)
#pragma unroll
        for (int qt2 = 0; qt2 < 4; ++qt2)
          acc[qt2][ddt] = __builtin_amdgcn_mfma_f32_16x16x32_f16(
              pf[qt2], xfB[ks][ddt], acc[qt2][ddt], 0, 0, 0);
    }
  };

  // ---- prologue: stage K tile 0 ----
  {
    f16x8 a0 = *(const f16x8*)kaSrc,       a1 = *(const f16x8*)(kaSrc + 8);
    f16x8 s0 = *(const f16x8*)ksSrc,       s1 = *(const f16x8*)(ksSrc + 8);
    *(f16x8*)&KaL[0][r0][hOff] = a0;  *(f16x8*)&KaL[0][r0][hOff + 8] = a1;
    *(f16x8*)&KsL[0][r0][hOff] = s0;  *(f16x8*)&KsL[0][r0][hOff + 8] = s1;
  }
  __syncthreads();

  // ---- main loop: 16 iters, one barrier each ----
  for (int k = 0; k < 16; ++k) {
    int buf = k & 1;
    if (k > 0) XFA(k - 1);                 // long latency cover (score+softmax)
    f16x8 a0, a1, s0, s1;
    if (k < 15) {
      size_t o = (size_t)(k + 1) * 128 * 32;
      a0 = *(const f16x8*)(kaSrc + o);  a1 = *(const f16x8*)(kaSrc + o + 8);
      s0 = *(const f16x8*)(ksSrc + o);  s1 = *(const f16x8*)(ksSrc + o + 8);
    }
    SCORE_MM(buf);                          // 16 ds_read + 16 MFMA
    if (k > 0) XFB(k - 1);                  // covered by softmax
    SCORE_FIN(buf);                         // softmax -> PL[buf]
    if (k > 0) { PVA(buf ^ 1); PVB(buf ^ 1); }  // 32 MFMA, xf ready
    if (k < 15) {
      *(f16x8*)&KaL[buf ^ 1][r0][hOff] = a0;
      *(f16x8*)&KaL[buf ^ 1][r0][hOff + 8] = a1;
      *(f16x8*)&KsL[buf ^ 1][r0][hOff] = s0;
      *(f16x8*)&KsL[buf ^ 1][r0][hOff + 8] = s1;
    }
    __syncthreads();
  }

  // ---- drain: PV for tile 15 (PL buffer 1) ----
  XFA(15); XFB(15);
  PVA(1);  PVB(1);

  // deferred l reduction
  l_lane += __shfl_xor(l_lane, 16, 64);
  l_lane += __shfl_xor(l_lane, 32, 64);
  if (g == 0) lL[wv * 16 + cl] = l_lane;
  __syncthreads();
#pragma unroll
  for (int qt2 = 0; qt2 < 4; ++qt2) {
#pragma unroll
    for (int r = 0; r < 4; ++r) {
      float linv = 1.0f / lL[qt2 * 16 + g * 4 + r];
      int q = qt * 64 + qt2 * 16 + g * 4 + r;
#pragma unroll
      for (int ddt = 0; ddt < 4; ++ddt) {
        float v = acc[qt2][ddt][r] * linv;
        int col = h * 256 + wv * 64 + ddt * 16 + cl;
        out[((size_t)b * 2048 + q) * 2048 + col] = v;
        if (q == 0) out_cls[(size_t)b * 2048 + col] = v;
      }
    }
  }
}

extern "C" void kernel_launch(void* const* d_in, const int* in_sizes, int n_in,
                              void* d_out, int out_size, void* d_ws, size_t ws_size,
                              hipStream_t stream) {
  const float* x  = (const float*)d_in[0];
  const float* af = (const float*)d_in[1];
  const float* Wq = (const float*)d_in[2];
  const float* Wa = (const float*)d_in[3];
  // ws (f16): Qs|Ks|Qa|Ka (4x1M) | xt (1M) | Wt (256K)  ~= 10.5 MB
  const size_t QK = (size_t)2 * 8 * 2048 * 32;
  f16* Qs = (f16*)d_ws;
  f16* Ks = Qs + QK;
  f16* Qa = Ks + QK;
  f16* Ka = Qa + QK;
  f16* xt = Ka + QK;
  f16* Wt = xt + QK;
  float* out     = (float*)d_out;
  float* out_cls = out + (size_t)2 * 2048 * 2048;
  float* attn0   = out_cls + 2 * 2048;

  k_stage<<<dim3(40, 4, 2), 256, 0, stream>>>(x, Wq, Wa, xt, Wt);
  k_proj<<<dim3(64, 8, 2), 256, 0, stream>>>(x, af, Wt, Qs, Ks, Qa, Ka);
  k_flash<<<dim3(33, 8, 2), 256, 0, stream>>>(Qs, Ks, Qa, Ka, xt, out, out_cls,
                                              attn0);
}

// Round 8
// 175.289 us; speedup vs baseline: 1.3638x; 1.0404x over previous
//
#include <hip/hip_runtime.h>

typedef _Float16 f16;
typedef _Float16 f16x4 __attribute__((ext_vector_type(4)));
typedef _Float16 f16x8 __attribute__((ext_vector_type(8)));
typedef float f32x4 __attribute__((ext_vector_type(4)));

#define LOG2E 1.4426950408889634f
#define SCL   (1.4426950408889634f / 32.0f)   // SCALE^2 * log2(e) folded
#define TH_RAW 177.445f                        // 8.0 / SCL : defer-max threshold

// ---------------- K0: fused transposes ---------------------------------------
// bx<32: x[b][2048][256] f32 -> xt[b][256][2048] f16   (tile n0=bx*64, d0=by*64)
// bx>=32: W[s][256][768] f32 -> Wt[s][512][256] f16    (n0=(bx-32)*64, k0=by*64)
__global__ __launch_bounds__(256) void k_stage(const float* __restrict__ x,
    const float* __restrict__ Wq, const float* __restrict__ Wa,
    f16* __restrict__ xt, f16* __restrict__ Wt) {
  __shared__ f16 tile[64][65];
  int t = threadIdx.x, c = t & 63, rg = t >> 6;
  if (blockIdx.x < 32) {
    int n0 = blockIdx.x * 64, d0 = blockIdx.y * 64, b = blockIdx.z;
#pragma unroll
    for (int r = 0; r < 16; ++r) {
      int row = r * 4 + rg;
      tile[row][c] = (f16)x[((size_t)b * 2048 + n0 + row) * 256 + d0 + c];
    }
    __syncthreads();
#pragma unroll
    for (int r = 0; r < 16; ++r) {
      int drow = r * 4 + rg;
      xt[((size_t)b * 256 + d0 + drow) * 2048 + n0 + c] = tile[c][drow];
    }
  } else {
    int n0 = (blockIdx.x - 32) * 64, k0 = blockIdx.y * 64, s = blockIdx.z;
    const float* W = s ? Wa : Wq;
    f16* dst = Wt + (size_t)s * 512 * 256;
#pragma unroll
    for (int r = 0; r < 16; ++r) {
      int krow = r * 4 + rg;
      tile[krow][c] = (f16)W[(size_t)(k0 + krow) * 768 + n0 + c];
    }
    __syncthreads();
#pragma unroll
    for (int r = 0; r < 16; ++r) {
      int nrow = r * 4 + rg;
      dst[(size_t)(n0 + nrow) * 256 + k0 + c] = tile[c][nrow];
    }
  }
}

// ---------------- K1: Q/K projections, global-direct (no LDS) ---------------
// Out: Q*/K* as [b*8+h][2048][32] f16.
__global__ __launch_bounds__(256) void k_proj(const float* __restrict__ x,
    const float* __restrict__ af, const f16* __restrict__ Wt,
    f16* __restrict__ Qs, f16* __restrict__ Ks,
    f16* __restrict__ Qa, f16* __restrict__ Ka) {
  int mt = blockIdx.x, nt = blockIdx.y, s = blockIdx.z;
  const float* A = s ? af : x;
  const f16* W = Wt + (size_t)s * 512 * 256;
  f16* Qd = s ? Qa : Qs;
  f16* Kd = s ? Ka : Ks;
  int t = threadIdx.x, wv = t >> 6, ln = t & 63, cl = ln & 15, g = ln >> 4;
  int m0 = mt * 64, n0 = nt * 64;
  const float* arow = A + (size_t)(m0 + wv * 16 + cl) * 256 + g * 8;
  const f16* wb = W + (size_t)n0 * 256 + g * 8;
  f32x4 z4 = {0.f, 0.f, 0.f, 0.f};
  f32x4 acc[4] = {z4, z4, z4, z4};
#pragma unroll
  for (int k32 = 0; k32 < 8; ++k32) {
    float4 u = *(const float4*)(arow + k32 * 32);
    float4 v = *(const float4*)(arow + k32 * 32 + 4);
    f16x8 a = { (f16)u.x, (f16)u.y, (f16)u.z, (f16)u.w,
                (f16)v.x, (f16)v.y, (f16)v.z, (f16)v.w };
#pragma unroll
    for (int n4 = 0; n4 < 4; ++n4) {
      f16x8 bf = *(const f16x8*)(wb + (size_t)(n4 * 16 + cl) * 256 + k32 * 32);
      acc[n4] = __builtin_amdgcn_mfma_f32_16x16x32_f16(a, bf, acc[n4], 0, 0, 0);
    }
  }
#pragma unroll
  for (int n4 = 0; n4 < 4; ++n4) {
    int c = n0 + n4 * 16 + cl;               // 0..511 (Q: 0-255, K: 256-511)
    int head = (c & 255) >> 5, d = c & 31;
    f16* dst = (c < 256) ? Qd : Kd;
#pragma unroll
    for (int r = 0; r < 4; ++r) {
      int m = m0 + wv * 16 + g * 4 + r;
      int bb = m >> 11, nn = m & 2047;
      dst[(((size_t)bb * 8 + head) * 2048 + nn) * 32 + d] = (f16)acc[n4][r];
    }
  }
}

// ---------------- K2: fused dual-score flash attention ----------------------
// bx==0: attn0 rider (row-0 probs), LDS aliased. bx>=1: flash, qt = bx-1.
// R2-proven structure (81us): block = 4 waves, 64 q-rows, KV tile = 64.
// Wave wv: scores q-stripe wv (16 rows); PV all 64 q x 64-dd slice wv*64,
// lagged one tile. K double-buffered in LDS; Xt frags direct from L2.
// Zero-shuffle defer-max common path; l-reduction deferred to epilogue.
// 256 threads + launch_bounds(256,2): only shape the allocator doesn't spill.
__global__ __launch_bounds__(256, 2) void k_flash(const f16* __restrict__ Qs,
    const f16* __restrict__ Ks, const f16* __restrict__ Qa,
    const f16* __restrict__ Ka, const f16* __restrict__ xt,
    float* __restrict__ out, float* __restrict__ out_cls,
    float* __restrict__ attn0) {
  __shared__ f16 KaL[2][64][40];     // pitch 80B
  __shared__ f16 KsL[2][64][40];
  __shared__ f16 PL[2][64][72];      // [q][j], pitch 144B
  __shared__ float alphaL[2][64] __attribute__((aligned(16)));
  __shared__ int   rsF[2][4] __attribute__((aligned(16)));
  __shared__ float lL[64];
  int h = blockIdx.y, b = blockIdx.z;
  int bh = b * 8 + h;
  int t = threadIdx.x;

  if (blockIdx.x == 0) {
    // ---- attn0 rider: probs for query row 0 (256 threads, LDS aliased) ----
    float* qa_s = &alphaL[0][0];
    float* qs_s = &alphaL[1][0];
    float* red  = (float*)&PL[0][0][0];    // 256 floats
    if (t < 32) {
      qa_s[t] = (float)Qa[(size_t)bh * 2048 * 32 + t];
      qs_s[t] = (float)Qs[(size_t)bh * 2048 * 32 + t];
    }
    __syncthreads();
    float sv[8];
#pragma unroll
    for (int r = 0; r < 8; ++r) {
      int j = r * 256 + t;
      const f16x8* ka8 = (const f16x8*)&Ka[((size_t)bh * 2048 + j) * 32];
      const f16x8* ks8 = (const f16x8*)&Ks[((size_t)bh * 2048 + j) * 32];
      float da = 0.f, ds = 0.f;
#pragma unroll
      for (int c = 0; c < 4; ++c) {
        f16x8 va = ka8[c], vs = ks8[c];
#pragma unroll
        for (int d = 0; d < 8; ++d) {
          da += qa_s[c * 8 + d] * (float)va[d];
          ds += qs_s[c * 8 + d] * (float)vs[d];
        }
      }
      sv[r] = da * ds * (1.f / 32.f);
    }
    float mx = sv[0];
#pragma unroll
    for (int r = 1; r < 8; ++r) mx = fmaxf(mx, sv[r]);
    red[t] = mx;
    __syncthreads();
    for (int st = 128; st > 0; st >>= 1) {
      if (t < st) red[t] = fmaxf(red[t], red[t + st]);
      __syncthreads();
    }
    float m = red[0];
    __syncthreads();
    float e[8], sum = 0.f;
#pragma unroll
    for (int r = 0; r < 8; ++r) {
      e[r] = exp2f((sv[r] - m) * LOG2E);
      sum += e[r];
    }
    red[t] = sum;
    __syncthreads();
    for (int st = 128; st > 0; st >>= 1) {
      if (t < st) red[t] += red[t + st];
      __syncthreads();
    }
    float l = red[0];
#pragma unroll
    for (int r = 0; r < 8; ++r)
      attn0[(size_t)b * 16384 + h * 2048 + r * 256 + t] = e[r] / l;
    return;
  }

  int qt = blockIdx.x - 1;
  int wv = t >> 6, ln = t & 63, cl = ln & 15, g = ln >> 4;
  int qrow0 = qt * 64 + wv * 16;
  f16x8 qsf = *(const f16x8*)&Qs[((size_t)bh * 2048 + qrow0 + cl) * 32 + g * 8];
  f16x8 qaf = *(const f16x8*)&Qa[((size_t)bh * 2048 + qrow0 + cl) * 32 + g * 8];
  f32x4 z4 = {0.f, 0.f, 0.f, 0.f};
  f32x4 acc[4][4];                   // [qt2][ddt]; D rows=q (g*4+r), cols=dd (cl)
#pragma unroll
  for (int i = 0; i < 4; ++i)
#pragma unroll
    for (int j = 0; j < 4; ++j) acc[i][j] = z4;
  float m_run = -3.0e38f, l_lane = 0.f;  // raw-domain max; per-lane l partial
  int krow = t >> 2, koff = (t & 3) * 8;
  const f16* kaSrc = Ka + ((size_t)bh * 2048 + krow) * 32 + koff;
  const f16* ksSrc = Ks + ((size_t)bh * 2048 + krow) * 32 + koff;
  const f16* xb = xt + ((size_t)b * 256 + wv * 64) * 2048;

  float tv[16];                      // raw dual scores for current tile
  f16x8 xf[2][4];                    // Xt B-frags for the lagged PV tile

  // ---- score MFMAs from KL[buf] -> tv (raw domain) ----
  auto SCORE_MM = [&](int buf) {
#pragma unroll
    for (int jt = 0; jt < 4; ++jt) {
      f16x8 kaf = *(const f16x8*)&KaL[buf][jt * 16 + cl][g * 8];
      f16x8 ksf = *(const f16x8*)&KsL[buf][jt * 16 + cl][g * 8];
      f32x4 za = __builtin_amdgcn_mfma_f32_16x16x32_f16(kaf, qaf, z4, 0, 0, 0);
      f32x4 zs = __builtin_amdgcn_mfma_f32_16x16x32_f16(ksf, qsf, z4, 0, 0, 0);
#pragma unroll
      for (int r = 0; r < 4; ++r) tv[jt * 4 + r] = za[r] * zs[r];
    }
  };

  // ---- softmax finish; zero-shuffle common path; deferred l-reduction ----
  auto SCORE_FIN = [&](int buf) {
    float a0 = fmaxf(tv[0], tv[1]),   a1 = fmaxf(tv[2], tv[3]);
    float a2 = fmaxf(tv[4], tv[5]),   a3 = fmaxf(tv[6], tv[7]);
    float a4 = fmaxf(tv[8], tv[9]),   a5 = fmaxf(tv[10], tv[11]);
    float a6 = fmaxf(tv[12], tv[13]), a7 = fmaxf(tv[14], tv[15]);
    float b0 = fmaxf(a0, a1), b1 = fmaxf(a2, a3);
    float b2 = fmaxf(a4, a5), b3 = fmaxf(a6, a7);
    float lmax = fmaxf(fmaxf(b0, b1), fmaxf(b2, b3));
    int wflag = 0;
    if (__any(lmax > m_run + TH_RAW)) {      // rare: real max growth
      float tm = fmaxf(lmax, __shfl_xor(lmax, 16, 64));
      tm = fmaxf(tm, __shfl_xor(tm, 32, 64));
      float m_new = fmaxf(m_run, tm);
      float alpha = exp2f((m_run - m_new) * SCL);
      l_lane *= alpha;
      m_run = m_new;
      if (g == 0) alphaL[buf][wv * 16 + cl] = alpha;
      wflag = 1;
    }
    float mS = m_run * SCL;
    float p[16];
#pragma unroll
    for (int i = 0; i < 16; ++i) p[i] = exp2f(fmaf(tv[i], SCL, -mS));
    float s0 = p[0] + p[1],   s1 = p[2] + p[3];
    float s2 = p[4] + p[5],   s3 = p[6] + p[7];
    float s4 = p[8] + p[9],   s5 = p[10] + p[11];
    float s6 = p[12] + p[13], s7 = p[14] + p[15];
    float u0 = s0 + s1, u1 = s2 + s3, u2 = s4 + s5, u3 = s6 + s7;
    l_lane += (u0 + u1) + (u2 + u3);         // per-lane partial; reduce at end
#pragma unroll
    for (int jt = 0; jt < 4; ++jt) {
      auto lo = __builtin_amdgcn_cvt_pkrtz(p[jt * 4 + 0], p[jt * 4 + 1]);
      auto hi = __builtin_amdgcn_cvt_pkrtz(p[jt * 4 + 2], p[jt * 4 + 3]);
      f16x4 pk = { (f16)lo[0], (f16)lo[1], (f16)hi[0], (f16)hi[1] };
      *(f16x4*)&PL[buf][wv * 16 + cl][jt * 16 + g * 4] = pk;
    }
    if (ln == 0) rsF[buf][wv] = wflag;
  };

  // ---- Xt B-frag loads for PV tile kt ----
  auto XFLOAD = [&](int kt) {
#pragma unroll
    for (int ks2 = 0; ks2 < 2; ++ks2)
#pragma unroll
      for (int ddt = 0; ddt < 4; ++ddt)
        xf[ks2][ddt] = *(const f16x8*)(xb + (size_t)(ddt * 16 + cl) * 2048 +
                                       kt * 64 + ks2 * 32 + g * 8);
  };

  // ---- PV for PL[pbuf] (lagged tile), with gated rescale ----
  auto PVDO = [&](int pbuf) {
    int4 fl = *(const int4*)&rsF[pbuf][0];
    int flq[4] = { fl.x, fl.y, fl.z, fl.w };
#pragma unroll
    for (int qt2 = 0; qt2 < 4; ++qt2) {
      if (flq[qt2]) {
        f32x4 a4 = *(const f32x4*)&alphaL[pbuf][qt2 * 16 + g * 4];
#pragma unroll
        for (int ddt = 0; ddt < 4; ++ddt)
#pragma unroll
          for (int r = 0; r < 4; ++r) acc[qt2][ddt][r] *= a4[r];
      }
    }
#pragma unroll
    for (int ks2 = 0; ks2 < 2; ++ks2) {
      f16x8 pf[4];
#pragma unroll
      for (int qt2 = 0; qt2 < 4; ++qt2)
        pf[qt2] = *(const f16x8*)&PL[pbuf][qt2 * 16 + cl][ks2 * 32 + g * 8];
#pragma unroll
      for (int ddt = 0; ddt < 4; ++ddt)
#pragma unroll
        for (int qt2 = 0; qt2 < 4; ++qt2)
          acc[qt2][ddt] = __builtin_amdgcn_mfma_f32_16x16x32_f16(
              pf[qt2], xf[ks2][ddt], acc[qt2][ddt], 0, 0, 0);
    }
  };

  // ---- prologue: stage K tile 0 ----
  *(f16x8*)&KaL[0][krow][koff] = *(const f16x8*)kaSrc;
  *(f16x8*)&KsL[0][krow][koff] = *(const f16x8*)ksSrc;
  __syncthreads();

  // I_0: score(0) only; commit K(1)
  f16x8 kan = *(const f16x8*)(kaSrc + 2048);
  f16x8 ksn = *(const f16x8*)(ksSrc + 2048);
  SCORE_MM(0);
  SCORE_FIN(0);
  *(f16x8*)&KaL[1][krow][koff] = kan;
  *(f16x8*)&KsL[1][krow][koff] = ksn;
  __syncthreads();

  // main loop: interval k = score(k) + PV(k-1)
  for (int k = 1; k < 32; ++k) {
    int sbuf = k & 1, pbuf = sbuf ^ 1;
    XFLOAD(k - 1);                           // global loads in flight early
    if (k < 31) {
      kan = *(const f16x8*)(kaSrc + (size_t)(k + 1) * 2048);
      ksn = *(const f16x8*)(ksSrc + (size_t)(k + 1) * 2048);
    }
    SCORE_MM(sbuf);                          // 8 MFMA (current tile)
    PVDO(pbuf);                              // 32 MFMA (lagged tile)
    SCORE_FIN(sbuf);                         // softmax VALU overlaps pipe drain
    if (k < 31) {
      *(f16x8*)&KaL[pbuf][krow][koff] = kan;
      *(f16x8*)&KsL[pbuf][krow][koff] = ksn;
    }
    __syncthreads();
  }

  // drain: PV tile 31 (PL buffer 1)
  XFLOAD(31);
  PVDO(1);

  // l reduction (deferred): once per kernel instead of per tile
  l_lane += __shfl_xor(l_lane, 16, 64);
  l_lane += __shfl_xor(l_lane, 32, 64);
  if (g == 0) lL[wv * 16 + cl] = l_lane;
  __syncthreads();
#pragma unroll
  for (int qt2 = 0; qt2 < 4; ++qt2) {
#pragma unroll
    for (int r = 0; r < 4; ++r) {
      float linv = 1.0f / lL[qt2 * 16 + g * 4 + r];
      int q = qt * 64 + qt2 * 16 + g * 4 + r;
#pragma unroll
      for (int ddt = 0; ddt < 4; ++ddt) {
        float v = acc[qt2][ddt][r] * linv;
        int col = h * 256 + wv * 64 + ddt * 16 + cl;
        out[((size_t)b * 2048 + q) * 2048 + col] = v;
        if (q == 0) out_cls[(size_t)b * 2048 + col] = v;
      }
    }
  }
}

extern "C" void kernel_launch(void* const* d_in, const int* in_sizes, int n_in,
                              void* d_out, int out_size, void* d_ws, size_t ws_size,
                              hipStream_t stream) {
  const float* x  = (const float*)d_in[0];
  const float* af = (const float*)d_in[1];
  const float* Wq = (const float*)d_in[2];
  const float* Wa = (const float*)d_in[3];
  // ws (f16): Qs|Ks|Qa|Ka (4x1M) | xt (1M) | Wt (256K)  ~= 10.5 MB
  const size_t QK = (size_t)2 * 8 * 2048 * 32;
  f16* Qs = (f16*)d_ws;
  f16* Ks = Qs + QK;
  f16* Qa = Ks + QK;
  f16* Ka = Qa + QK;
  f16* xt = Ka + QK;
  f16* Wt = xt + QK;
  float* out     = (float*)d_out;
  float* out_cls = out + (size_t)2 * 2048 * 2048;
  float* attn0   = out_cls + 2 * 2048;

  k_stage<<<dim3(40, 4, 2), 256, 0, stream>>>(x, Wq, Wa, xt, Wt);
  k_proj<<<dim3(64, 8, 2), 256, 0, stream>>>(x, af, Wt, Qs, Ks, Qa, Ka);
  k_flash<<<dim3(33, 8, 2), 256, 0, stream>>>(Qs, Ks, Qa, Ka, xt, out, out_cls,
                                              attn0);
}

// Round 10
// 173.204 us; speedup vs baseline: 1.3803x; 1.0120x over previous
//
#include <hip/hip_runtime.h>

typedef _Float16 f16;
typedef _Float16 f16x4 __attribute__((ext_vector_type(4)));
typedef _Float16 f16x8 __attribute__((ext_vector_type(8)));
typedef float f32x4 __attribute__((ext_vector_type(4)));

#define LOG2E 1.4426950408889634f
#define SCL   (1.4426950408889634f / 32.0f)   // SCALE^2 * log2(e) folded
#define TH_RAW 177.445f                        // 8.0 / SCL : defer-max threshold

// ---------------- K0: W[s][256][768] f32 -> Wt[s][512][256] f16 (Q|K cols) --
__global__ __launch_bounds__(256) void k_W(const float* __restrict__ Wq,
    const float* __restrict__ Wa, f16* __restrict__ Wt) {
  __shared__ f16 tile[64][65];
  int n0 = blockIdx.x * 64, k0 = blockIdx.y * 64, s = blockIdx.z;
  const float* W = s ? Wa : Wq;
  f16* dst = Wt + (size_t)s * 512 * 256;
  int t = threadIdx.x, c = t & 63, rg = t >> 6;
#pragma unroll
  for (int r = 0; r < 16; ++r) {
    int krow = r * 4 + rg;
    tile[krow][c] = (f16)W[(size_t)(k0 + krow) * 768 + n0 + c];
  }
  __syncthreads();
#pragma unroll
  for (int r = 0; r < 16; ++r) {
    int nrow = r * 4 + rg;
    dst[(size_t)(n0 + nrow) * 256 + k0 + c] = tile[c][nrow];
  }
}

// ---------------- K1: Q/K projections + x-transpose riders -------------------
// bx<64: proj block (mt=bx, nt=by, s=bz). Out Q*/K* as [b*8+h][2048][32] f16.
// bx>=64: x-transpose rider: x[b][2048][256] f32 -> xt[b][256][2048] f16,
//         independent of proj (overlaps it in the same launch).
__global__ __launch_bounds__(256) void k_proj(const float* __restrict__ x,
    const float* __restrict__ af, const f16* __restrict__ Wt,
    f16* __restrict__ Qs, f16* __restrict__ Ks,
    f16* __restrict__ Qa, f16* __restrict__ Ka, f16* __restrict__ xt) {
  __shared__ f16 tile[64][65];
  int t = threadIdx.x;
  if (blockIdx.x >= 64) {
    // ---- x-transpose rider ----
    int r = ((blockIdx.z * 8 + blockIdx.y) * 16 + (blockIdx.x - 64));
    int n0 = (r & 31) * 64, d0 = ((r >> 5) & 3) * 64, b = r >> 7;
    int c = t & 63, rg = t >> 6;
#pragma unroll
    for (int rr = 0; rr < 16; ++rr) {
      int row = rr * 4 + rg;
      tile[row][c] = (f16)x[((size_t)b * 2048 + n0 + row) * 256 + d0 + c];
    }
    __syncthreads();
#pragma unroll
    for (int rr = 0; rr < 16; ++rr) {
      int drow = rr * 4 + rg;
      xt[((size_t)b * 256 + d0 + drow) * 2048 + n0 + c] = tile[c][drow];
    }
    return;
  }
  int mt = blockIdx.x, nt = blockIdx.y, s = blockIdx.z;
  const float* A = s ? af : x;
  const f16* W = Wt + (size_t)s * 512 * 256;
  f16* Qd = s ? Qa : Qs;
  f16* Kd = s ? Ka : Ks;
  int wv = t >> 6, ln = t & 63, cl = ln & 15, g = ln >> 4;
  int m0 = mt * 64, n0 = nt * 64;
  const float* arow = A + (size_t)(m0 + wv * 16 + cl) * 256 + g * 8;
  const f16* wb = W + (size_t)n0 * 256 + g * 8;
  f32x4 z4 = {0.f, 0.f, 0.f, 0.f};
  f32x4 acc[4] = {z4, z4, z4, z4};
#pragma unroll
  for (int k32 = 0; k32 < 8; ++k32) {
    float4 u = *(const float4*)(arow + k32 * 32);
    float4 v = *(const float4*)(arow + k32 * 32 + 4);
    f16x8 a = { (f16)u.x, (f16)u.y, (f16)u.z, (f16)u.w,
                (f16)v.x, (f16)v.y, (f16)v.z, (f16)v.w };
#pragma unroll
    for (int n4 = 0; n4 < 4; ++n4) {
      f16x8 bf = *(const f16x8*)(wb + (size_t)(n4 * 16 + cl) * 256 + k32 * 32);
      acc[n4] = __builtin_amdgcn_mfma_f32_16x16x32_f16(a, bf, acc[n4], 0, 0, 0);
    }
  }
#pragma unroll
  for (int n4 = 0; n4 < 4; ++n4) {
    int c = n0 + n4 * 16 + cl;               // 0..511 (Q: 0-255, K: 256-511)
    int head = (c & 255) >> 5, d = c & 31;
    f16* dst = (c < 256) ? Qd : Kd;
#pragma unroll
    for (int r = 0; r < 4; ++r) {
      int m = m0 + wv * 16 + g * 4 + r;
      int bb = m >> 11, nn = m & 2047;
      dst[(((size_t)bb * 8 + head) * 2048 + nn) * 32 + d] = (f16)acc[n4][r];
    }
  }
}

// ---------------- K2: fused dual-score flash attention ----------------------
// bx==0: attn0 rider (row-0 probs), shuffle-reduced, ~2 barriers -> small tail.
// bx>=1: flash, qt = bx-1. R2-proven structure (81us): 4 waves, 64 q-rows,
// KV tile = 64, K dbuf in LDS, Xt frags from L2, zero-shuffle defer-max,
// deferred l-reduction. 256 threads + launch_bounds(256,2): no-spill shape.
__global__ __launch_bounds__(256, 2) void k_flash(const f16* __restrict__ Qs,
    const f16* __restrict__ Ks, const f16* __restrict__ Qa,
    const f16* __restrict__ Ka, const f16* __restrict__ xt,
    float* __restrict__ out, float* __restrict__ out_cls,
    float* __restrict__ attn0) {
  __shared__ f16 KaL[2][64][40];     // pitch 80B
  __shared__ f16 KsL[2][64][40];
  __shared__ f16 PL[2][64][72];      // [q][j], pitch 144B
  __shared__ float alphaL[2][64] __attribute__((aligned(16)));
  __shared__ int   rsF[2][4] __attribute__((aligned(16)));
  __shared__ float lL[64];
  int h = blockIdx.y, b = blockIdx.z;
  int bh = b * 8 + h;
  int t = threadIdx.x;

  if (blockIdx.x == 0) {
    // ---- attn0 rider: probs for query row 0; wave-shuffle reductions ----
    int wv = t >> 6;
    f16x8 qa8[4], qs8[4];
#pragma unroll
    for (int c = 0; c < 4; ++c) {            // uniform address: L1 broadcast
      qa8[c] = *(const f16x8*)&Qa[(size_t)bh * 2048 * 32 + c * 8];
      qs8[c] = *(const f16x8*)&Qs[(size_t)bh * 2048 * 32 + c * 8];
    }
    float sv[8];
#pragma unroll
    for (int r = 0; r < 8; ++r) {
      int j = r * 256 + t;
      const f16x8* ka8 = (const f16x8*)&Ka[((size_t)bh * 2048 + j) * 32];
      const f16x8* ks8 = (const f16x8*)&Ks[((size_t)bh * 2048 + j) * 32];
      float da = 0.f, ds = 0.f;
#pragma unroll
      for (int c = 0; c < 4; ++c) {
        f16x8 va = ka8[c], vs = ks8[c];
#pragma unroll
        for (int d = 0; d < 8; ++d) {
          da += (float)qa8[c][d] * (float)va[d];
          ds += (float)qs8[c][d] * (float)vs[d];
        }
      }
      sv[r] = da * ds * (1.f / 32.f);
    }
    float mx = sv[0];
#pragma unroll
    for (int r = 1; r < 8; ++r) mx = fmaxf(mx, sv[r]);
#pragma unroll
    for (int off = 1; off < 64; off <<= 1)
      mx = fmaxf(mx, __shfl_xor(mx, off, 64));
    if ((t & 63) == 0) lL[wv] = mx;
    __syncthreads();
    float m = fmaxf(fmaxf(lL[0], lL[1]), fmaxf(lL[2], lL[3]));
    float e[8], sum = 0.f;
#pragma unroll
    for (int r = 0; r < 8; ++r) {
      e[r] = exp2f((sv[r] - m) * LOG2E);
      sum += e[r];
    }
#pragma unroll
    for (int off = 1; off < 64; off <<= 1)
      sum += __shfl_xor(sum, off, 64);
    if ((t & 63) == 0) lL[4 + wv] = sum;
    __syncthreads();
    float l = (lL[4] + lL[5]) + (lL[6] + lL[7]);
#pragma unroll
    for (int r = 0; r < 8; ++r)
      attn0[(size_t)b * 16384 + h * 2048 + r * 256 + t] = e[r] / l;
    return;
  }

  int qt = blockIdx.x - 1;
  int wv = t >> 6, ln = t & 63, cl = ln & 15, g = ln >> 4;
  int qrow0 = qt * 64 + wv * 16;
  f16x8 qsf = *(const f16x8*)&Qs[((size_t)bh * 2048 + qrow0 + cl) * 32 + g * 8];
  f16x8 qaf = *(const f16x8*)&Qa[((size_t)bh * 2048 + qrow0 + cl) * 32 + g * 8];
  f32x4 z4 = {0.f, 0.f, 0.f, 0.f};
  f32x4 acc[4][4];                   // [qt2][ddt]; D rows=q (g*4+r), cols=dd (cl)
#pragma unroll
  for (int i = 0; i < 4; ++i)
#pragma unroll
    for (int j = 0; j < 4; ++j) acc[i][j] = z4;
  float m_run = -3.0e38f, l_lane = 0.f;  // raw-domain max; per-lane l partial
  int krow = t >> 2, koff = (t & 3) * 8;
  const f16* kaSrc = Ka + ((size_t)bh * 2048 + krow) * 32 + koff;
  const f16* ksSrc = Ks + ((size_t)bh * 2048 + krow) * 32 + koff;
  const f16* xb = xt + ((size_t)b * 256 + wv * 64) * 2048;

  float tv[16];                      // raw dual scores for current tile
  f16x8 xf[2][4];                    // Xt B-frags for the lagged PV tile

  // ---- score MFMAs from KL[buf] -> tv (raw domain) ----
  auto SCORE_MM = [&](int buf) {
#pragma unroll
    for (int jt = 0; jt < 4; ++jt) {
      f16x8 kaf = *(const f16x8*)&KaL[buf][jt * 16 + cl][g * 8];
      f16x8 ksf = *(const f16x8*)&KsL[buf][jt * 16 + cl][g * 8];
      f32x4 za = __builtin_amdgcn_mfma_f32_16x16x32_f16(kaf, qaf, z4, 0, 0, 0);
      f32x4 zs = __builtin_amdgcn_mfma_f32_16x16x32_f16(ksf, qsf, z4, 0, 0, 0);
#pragma unroll
      for (int r = 0; r < 4; ++r) tv[jt * 4 + r] = za[r] * zs[r];
    }
  };

  // ---- softmax finish; zero-shuffle common path; deferred l-reduction ----
  auto SCORE_FIN = [&](int buf) {
    float a0 = fmaxf(tv[0], tv[1]),   a1 = fmaxf(tv[2], tv[3]);
    float a2 = fmaxf(tv[4], tv[5]),   a3 = fmaxf(tv[6], tv[7]);
    float a4 = fmaxf(tv[8], tv[9]),   a5 = fmaxf(tv[10], tv[11]);
    float a6 = fmaxf(tv[12], tv[13]), a7 = fmaxf(tv[14], tv[15]);
    float b0 = fmaxf(a0, a1), b1 = fmaxf(a2, a3);
    float b2 = fmaxf(a4, a5), b3 = fmaxf(a6, a7);
    float lmax = fmaxf(fmaxf(b0, b1), fmaxf(b2, b3));
    int wflag = 0;
    if (__any(lmax > m_run + TH_RAW)) {      // rare: real max growth
      float tm = fmaxf(lmax, __shfl_xor(lmax, 16, 64));
      tm = fmaxf(tm, __shfl_xor(tm, 32, 64));
      float m_new = fmaxf(m_run, tm);
      float alpha = exp2f((m_run - m_new) * SCL);
      l_lane *= alpha;
      m_run = m_new;
      if (g == 0) alphaL[buf][wv * 16 + cl] = alpha;
      wflag = 1;
    }
    float mS = m_run * SCL;
    float p[16];
#pragma unroll
    for (int i = 0; i < 16; ++i) p[i] = exp2f(fmaf(tv[i], SCL, -mS));
    float s0 = p[0] + p[1],   s1 = p[2] + p[3];
    float s2 = p[4] + p[5],   s3 = p[6] + p[7];
    float s4 = p[8] + p[9],   s5 = p[10] + p[11];
    float s6 = p[12] + p[13], s7 = p[14] + p[15];
    float u0 = s0 + s1, u1 = s2 + s3, u2 = s4 + s5, u3 = s6 + s7;
    l_lane += (u0 + u1) + (u2 + u3);         // per-lane partial; reduce at end
#pragma unroll
    for (int jt = 0; jt < 4; ++jt) {
      auto lo = __builtin_amdgcn_cvt_pkrtz(p[jt * 4 + 0], p[jt * 4 + 1]);
      auto hi = __builtin_amdgcn_cvt_pkrtz(p[jt * 4 + 2], p[jt * 4 + 3]);
      f16x4 pk = { (f16)lo[0], (f16)lo[1], (f16)hi[0], (f16)hi[1] };
      *(f16x4*)&PL[buf][wv * 16 + cl][jt * 16 + g * 4] = pk;
    }
    if (ln == 0) rsF[buf][wv] = wflag;
  };

  // ---- Xt B-frag loads for PV tile kt ----
  auto XFLOAD = [&](int kt) {
#pragma unroll
    for (int ks2 = 0; ks2 < 2; ++ks2)
#pragma unroll
      for (int ddt = 0; ddt < 4; ++ddt)
        xf[ks2][ddt] = *(const f16x8*)(xb + (size_t)(ddt * 16 + cl) * 2048 +
                                       kt * 64 + ks2 * 32 + g * 8);
  };

  // ---- PV for PL[pbuf] (lagged tile), with gated rescale ----
  auto PVDO = [&](int pbuf) {
    int4 fl = *(const int4*)&rsF[pbuf][0];
    int flq[4] = { fl.x, fl.y, fl.z, fl.w };
#pragma unroll
    for (int qt2 = 0; qt2 < 4; ++qt2) {
      if (flq[qt2]) {
        f32x4 a4 = *(const f32x4*)&alphaL[pbuf][qt2 * 16 + g * 4];
#pragma unroll
        for (int ddt = 0; ddt < 4; ++ddt)
#pragma unroll
          for (int r = 0; r < 4; ++r) acc[qt2][ddt][r] *= a4[r];
      }
    }
#pragma unroll
    for (int ks2 = 0; ks2 < 2; ++ks2) {
      f16x8 pf[4];
#pragma unroll
      for (int qt2 = 0; qt2 < 4; ++qt2)
        pf[qt2] = *(const f16x8*)&PL[pbuf][qt2 * 16 + cl][ks2 * 32 + g * 8];
#pragma unroll
      for (int ddt = 0; ddt < 4; ++ddt)
#pragma unroll
        for (int qt2 = 0; qt2 < 4; ++qt2)
          acc[qt2][ddt] = __builtin_amdgcn_mfma_f32_16x16x32_f16(
              pf[qt2], xf[ks2][ddt], acc[qt2][ddt], 0, 0, 0);
    }
  };

  // ---- prologue: stage K tile 0 ----
  *(f16x8*)&KaL[0][krow][koff] = *(const f16x8*)kaSrc;
  *(f16x8*)&KsL[0][krow][koff] = *(const f16x8*)ksSrc;
  __syncthreads();

  // I_0: score(0) only; commit K(1)
  f16x8 kan = *(const f16x8*)(kaSrc + 2048);
  f16x8 ksn = *(const f16x8*)(ksSrc + 2048);
  SCORE_MM(0);
  SCORE_FIN(0);
  *(f16x8*)&KaL[1][krow][koff] = kan;
  *(f16x8*)&KsL[1][krow][koff] = ksn;
  __syncthreads();

  // main loop: interval k = score(k) + PV(k-1)
  for (int k = 1; k < 32; ++k) {
    int sbuf = k & 1, pbuf = sbuf ^ 1;
    XFLOAD(k - 1);                           // global loads in flight early
    if (k < 31) {
      kan = *(const f16x8*)(kaSrc + (size_t)(k + 1) * 2048);
      ksn = *(const f16x8*)(ksSrc + (size_t)(k + 1) * 2048);
    }
    SCORE_MM(sbuf);                          // 8 MFMA (current tile)
    PVDO(pbuf);                              // 32 MFMA (lagged tile)
    SCORE_FIN(sbuf);                         // softmax VALU overlaps pipe drain
    if (k < 31) {
      *(f16x8*)&KaL[pbuf][krow][koff] = kan;
      *(f16x8*)&KsL[pbuf][krow][koff] = ksn;
    }
    __syncthreads();
  }

  // drain: PV tile 31 (PL buffer 1)
  XFLOAD(31);
  PVDO(1);

  // l reduction (deferred): once per kernel instead of per tile
  l_lane += __shfl_xor(l_lane, 16, 64);
  l_lane += __shfl_xor(l_lane, 32, 64);
  if (g == 0) lL[wv * 16 + cl] = l_lane;
  __syncthreads();
#pragma unroll
  for (int qt2 = 0; qt2 < 4; ++qt2) {
#pragma unroll
    for (int r = 0; r < 4; ++r) {
      float linv = 1.0f / lL[qt2 * 16 + g * 4 + r];
      int q = qt * 64 + qt2 * 16 + g * 4 + r;
#pragma unroll
      for (int ddt = 0; ddt < 4; ++ddt) {
        float v = acc[qt2][ddt][r] * linv;
        int col = h * 256 + wv * 64 + ddt * 16 + cl;
        out[((size_t)b * 2048 + q) * 2048 + col] = v;
        if (q == 0) out_cls[(size_t)b * 2048 + col] = v;
      }
    }
  }
}

extern "C" void kernel_launch(void* const* d_in, const int* in_sizes, int n_in,
                              void* d_out, int out_size, void* d_ws, size_t ws_size,
                              hipStream_t stream) {
  const float* x  = (const float*)d_in[0];
  const float* af = (const float*)d_in[1];
  const float* Wq = (const float*)d_in[2];
  const float* Wa = (const float*)d_in[3];
  // ws (f16): Qs|Ks|Qa|Ka (4x1M) | xt (1M) | Wt (256K)  ~= 10.5 MB
  const size_t QK = (size_t)2 * 8 * 2048 * 32;
  f16* Qs = (f16*)d_ws;
  f16* Ks = Qs + QK;
  f16* Qa = Ks + QK;
  f16* Ka = Qa + QK;
  f16* xt = Ka + QK;
  f16* Wt = xt + QK;
  float* out     = (float*)d_out;
  float* out_cls = out + (size_t)2 * 2048 * 2048;
  float* attn0   = out_cls + 2 * 2048;

  k_W<<<dim3(8, 4, 2), 256, 0, stream>>>(Wq, Wa, Wt);
  k_proj<<<dim3(80, 8, 2), 256, 0, stream>>>(x, af, Wt, Qs, Ks, Qa, Ka, xt);
  k_flash<<<dim3(33, 8, 2), 256, 0, stream>>>(Qs, Ks, Qa, Ka, xt, out, out_cls,
                                              attn0);
}